// Round 4
// baseline (581.658 us; speedup 1.0000x reference)
//
#include <hip/hip_runtime.h>

#define NN 50000
#define DD 128
#define NE 800000
#define BN_EPS 1e-5f

// ---------------- CSR build ----------------
__global__ void k_hist(const int* __restrict__ dst, int* __restrict__ cnt, int ne) {
    int i = blockIdx.x * blockDim.x + threadIdx.x;
    if (i < ne) atomicAdd(&cnt[dst[i]], 1);
}

// phase A: per-block sums of cnt (coalesced)
__global__ __launch_bounds__(256) void k_bsum(const int* __restrict__ cnt,
                                              int* __restrict__ bsum, int n) {
    __shared__ int red[256];
    int i = blockIdx.x * 256 + threadIdx.x;
    int v = (i < n) ? cnt[i] : 0;
    red[threadIdx.x] = v;
    __syncthreads();
    for (int off = 128; off > 0; off >>= 1) {
        if (threadIdx.x < off) red[threadIdx.x] += red[threadIdx.x + off];
        __syncthreads();
    }
    if (threadIdx.x == 0) bsum[blockIdx.x] = red[0];
}

// phase B: inclusive scan of block sums (nb <= 256) in one block
__global__ __launch_bounds__(256) void k_bscan(int* __restrict__ bsum, int nb) {
    __shared__ int sh[256];
    int t = threadIdx.x;
    sh[t] = (t < nb) ? bsum[t] : 0;
    __syncthreads();
    for (int off = 1; off < 256; off <<= 1) {
        int add = (t >= off) ? sh[t - off] : 0;
        __syncthreads();
        sh[t] += add;
        __syncthreads();
    }
    if (t < nb) bsum[t] = sh[t];
}

// phase C: per-block exclusive prefix + write rowp/cursor/dinv (coalesced)
__global__ __launch_bounds__(256) void k_rowp(const int* __restrict__ cnt,
                                              const int* __restrict__ bsum,
                                              int* __restrict__ rowp,
                                              int* __restrict__ cursor,
                                              float* __restrict__ dinv, int n) {
    __shared__ int sh[256];
    int t = threadIdx.x;
    int i = blockIdx.x * 256 + t;
    int v = (i < n) ? cnt[i] : 0;
    sh[t] = v;
    __syncthreads();
    for (int off = 1; off < 256; off <<= 1) {
        int add = (t >= off) ? sh[t - off] : 0;
        __syncthreads();
        sh[t] += add;
        __syncthreads();
    }
    int base = (blockIdx.x > 0) ? bsum[blockIdx.x - 1] : 0;
    int excl = base + sh[t] - v;
    if (i < n) {
        rowp[i] = excl;
        cursor[i] = excl;
        dinv[i] = 1.0f / sqrtf((float)(v + 1));
        if (i == n - 1) rowp[n] = excl + v;
    }
}

__global__ void k_scatter(const int* __restrict__ src, const int* __restrict__ dst,
                          int* __restrict__ cursor, int* __restrict__ col,
                          float* __restrict__ val, const float* __restrict__ dinv,
                          int ne) {
    int i = blockIdx.x * blockDim.x + threadIdx.x;
    if (i < ne) {
        int d = dst[i], s = src[i];
        int pos = atomicAdd(&cursor[d], 1);
        col[pos] = s;
        val[pos] = dinv[s];
    }
}

// ---------------- GEMM: C[n,128] = A[n,128] * W[128,128] ----------------
#define GROWS 32
__global__ __launch_bounds__(256) void k_gemm(const float* __restrict__ A,
                                              const float* __restrict__ W,
                                              float* __restrict__ C, int n) {
    __shared__ float sA[GROWS][DD];   // 16 KB
    __shared__ float sW[DD][DD];      // 64 KB
    int tid = threadIdx.x;
    int row0 = blockIdx.x * GROWS;

    {
        const float4* Wv = (const float4*)W;
        float4* sWv = (float4*)&sW[0][0];
        for (int i = tid; i < DD * DD / 4; i += 256) sWv[i] = Wv[i];
    }
    {
        const float4* Av = (const float4*)(A + (size_t)row0 * DD);
        float4* sAv = (float4*)&sA[0][0];
        for (int i = tid; i < GROWS * DD / 4; i += 256) {
            int r = i >> 5;
            float4 v = make_float4(0.f, 0.f, 0.f, 0.f);
            if (row0 + r < n) v = Av[i];
            sAv[i] = v;
        }
    }
    __syncthreads();

    int tx = tid & 31;
    int ty = tid >> 5;
    float acc[4][4] = {};
    for (int k = 0; k < DD; k += 4) {
        float a[4][4], b[4][4];
        #pragma unroll
        for (int r = 0; r < 4; r++)
            *(float4*)a[r] = *(const float4*)&sA[ty * 4 + r][k];
        #pragma unroll
        for (int kk = 0; kk < 4; kk++)
            *(float4*)b[kk] = *(const float4*)&sW[k + kk][tx * 4];
        #pragma unroll
        for (int r = 0; r < 4; r++)
            #pragma unroll
            for (int kk = 0; kk < 4; kk++)
                #pragma unroll
                for (int c = 0; c < 4; c++)
                    acc[r][c] += a[r][kk] * b[kk][c];
    }
    #pragma unroll
    for (int r = 0; r < 4; r++) {
        int row = row0 + ty * 4 + r;
        if (row < n)
            *(float4*)(C + (size_t)row * DD + tx * 4) = *(float4*)acc[r];
    }
}

// ---------------- aggregation: XCD-local feature slicing ----------------
// slice = blockIdx % 8 -> 16 features (64B). Blocks dispatch round-robin over
// the 8 XCDs, so each XCD gathers from a 3.2 MB slice of h that fits its 4 MB
// L2. 4 lanes x float4 per node; a wave processes 16 nodes concurrently.
#define AGG_NPB 64   // nodes per block (256 thr / 4 lanes-per-node)
__global__ __launch_bounds__(256) void k_agg(const float* __restrict__ h,
                                             const int* __restrict__ rowp,
                                             const int* __restrict__ col,
                                             const float* __restrict__ val,
                                             const float* __restrict__ dinv,
                                             const float* __restrict__ bias,
                                             float* __restrict__ out, int n) {
    int slice = blockIdx.x & 7;
    int chunk = blockIdx.x >> 3;
    int grp = threadIdx.x >> 2;      // 0..63: node within chunk
    int sub = threadIdx.x & 3;       // 0..3: float4 within slice
    int node = chunk * AGG_NPB + grp;
    if (node >= n) return;
    int f = slice * 16 + sub * 4;
    int beg = rowp[node], end = rowp[node + 1];
    float4 acc = make_float4(0.f, 0.f, 0.f, 0.f);
    #pragma unroll 4
    for (int e = beg; e < end; e++) {
        int s = col[e];
        float w = val[e];
        float4 hv = *(const float4*)(h + (size_t)s * DD + f);
        acc.x += w * hv.x;
        acc.y += w * hv.y;
        acc.z += w * hv.z;
        acc.w += w * hv.w;
    }
    float di = dinv[node];
    float dii = di * di;
    float4 hs = *(const float4*)(h + (size_t)node * DD + f);
    float4 bv = *(const float4*)(bias + f);
    float4 o;
    o.x = di * acc.x + dii * hs.x + bv.x;
    o.y = di * acc.y + dii * hs.y + bv.y;
    o.z = di * acc.z + dii * hs.z + bv.z;
    o.w = di * acc.w + dii * hs.w + bv.w;
    *(float4*)(out + (size_t)node * DD + f) = o;
}

// ---------------- BN stats: per-feature sum & sumsq ----------------
#define SROWS 64
__global__ __launch_bounds__(128) void k_stats(const float* __restrict__ X,
                                               float* __restrict__ sums, int n) {
    int f = threadIdx.x;
    int r0 = blockIdx.x * SROWS;
    int r1 = min(r0 + SROWS, n);
    float s = 0.f, s2 = 0.f;
    for (int r = r0; r < r1; r++) {
        float v = X[(size_t)r * DD + f];
        s += v;
        s2 += v * v;
    }
    atomicAdd(&sums[f], s);
    atomicAdd(&sums[DD + f], s2);
}

// ---------------- BN apply + ReLU + residual ----------------
__global__ __launch_bounds__(256) void k_bn(const float* __restrict__ X,
                                            const float* __restrict__ res,
                                            const float* __restrict__ sums,
                                            const float* __restrict__ gamma,
                                            const float* __restrict__ beta,
                                            float* __restrict__ out, int n) {
    int idx = blockIdx.x * blockDim.x + threadIdx.x;
    int total = n * (DD / 4);
    if (idx >= total) return;
    int f = (idx & 31) * 4;
    float4 v = ((const float4*)X)[idx];
    float4 rv = ((const float4*)res)[idx];
    float o[4];
    float vi[4] = {v.x, v.y, v.z, v.w};
    float ri[4] = {rv.x, rv.y, rv.z, rv.w};
    float inv_n = 1.0f / (float)n;
    #pragma unroll
    for (int j = 0; j < 4; j++) {
        float mean = sums[f + j] * inv_n;
        float var = sums[DD + f + j] * inv_n - mean * mean;
        float x = (vi[j] - mean) * (1.0f / sqrtf(var + BN_EPS)) * gamma[f + j] + beta[f + j];
        x = fmaxf(x, 0.f);
        o[j] = x + ri[j];
    }
    ((float4*)out)[idx] = make_float4(o[0], o[1], o[2], o[3]);
}

// ---------------- attention: grid-stride waves, one atomic per block ----------------
#define ATT_BLOCKS 256
__global__ __launch_bounds__(256) void k_att(const float* __restrict__ H,
                                             const float* __restrict__ Wa,
                                             const float* __restrict__ ba,
                                             float* __restrict__ evec,
                                             float* __restrict__ Z, int n) {
    int wave = threadIdx.x >> 6;
    int lane = threadIdx.x & 63;
    int gw = blockIdx.x * 4 + wave;
    int nw = gridDim.x * 4;
    float2 wv = *(const float2*)(Wa + lane * 2);
    float bb = ba[0];
    float lsum = 0.f;
    for (int node = gw; node < n; node += nw) {
        float2 hv = *(const float2*)(H + (size_t)node * DD + lane * 2);
        float t = hv.x * wv.x + hv.y * wv.y;
        #pragma unroll
        for (int off = 1; off < 64; off <<= 1) t += __shfl_xor(t, off);
        float ev = expf(tanhf(t + bb));
        if (lane == 0) {
            evec[node] = ev;
            lsum += ev;
        }
    }
    __shared__ float part[4];
    if (lane == 0) part[wave] = lsum;
    __syncthreads();
    if (threadIdx.x == 0)
        atomicAdd(Z, part[0] + part[1] + part[2] + part[3]);
}

// ---------------- final: out = h * e / Z ----------------
__global__ __launch_bounds__(256) void k_out(const float* __restrict__ H,
                                             const float* __restrict__ evec,
                                             const float* __restrict__ Z,
                                             float* __restrict__ out, int n) {
    int idx = blockIdx.x * blockDim.x + threadIdx.x;
    int total = n * (DD / 4);
    if (idx >= total) return;
    int node = idx >> 5;
    float s = evec[node] / Z[0];
    float4 h = ((const float4*)H)[idx];
    ((float4*)out)[idx] = make_float4(h.x * s, h.y * s, h.z * s, h.w * s);
}

extern "C" void kernel_launch(void* const* d_in, const int* in_sizes, int n_in,
                              void* d_out, int out_size, void* d_ws, size_t ws_size,
                              hipStream_t stream) {
    const float* x   = (const float*)d_in[0];
    const int* eidx  = (const int*)d_in[1];
    const float* W1  = (const float*)d_in[2];
    const float* b1  = (const float*)d_in[3];
    const float* g1  = (const float*)d_in[4];
    const float* be1 = (const float*)d_in[5];
    const float* W2  = (const float*)d_in[6];
    const float* b2  = (const float*)d_in[7];
    const float* g2  = (const float*)d_in[8];
    const float* be2 = (const float*)d_in[9];
    const float* Wa  = (const float*)d_in[10];
    const float* ba  = (const float*)d_in[11];
    float* out = (float*)d_out;

    const int* srcp = eidx;
    const int* dstp = eidx + NE;

    float* bufA = (float*)d_ws;              // N*D
    float* bufB = bufA + (size_t)NN * DD;    // N*D
    float* bufC = bufB + (size_t)NN * DD;    // N*D
    float* val  = bufC + (size_t)NN * DD;    // NE
    float* dinv = val + NE;                  // NN
    float* evec = dinv + NN;                 // NN
    float* sums = evec + NN;                 // 256
    float* Z    = sums + 256;                // 1 (pad 64)
    int* cnt    = (int*)(Z + 64);            // NN
    int* rowp   = cnt + NN;                  // NN+1 (pad 64)
    int* cursor = rowp + NN + 64;            // NN
    int* col    = cursor + NN;               // NE
    int* bsum   = col + NE;                  // 256

    const int nscan = (NN + 255) / 256;      // 196 blocks

    // ---- CSR build ----
    hipMemsetAsync(cnt, 0, (size_t)NN * sizeof(int), stream);
    hipMemsetAsync(Z, 0, sizeof(float), stream);
    k_hist<<<(NE + 255) / 256, 256, 0, stream>>>(dstp, cnt, NE);
    k_bsum<<<nscan, 256, 0, stream>>>(cnt, bsum, NN);
    k_bscan<<<1, 256, 0, stream>>>(bsum, nscan);
    k_rowp<<<nscan, 256, 0, stream>>>(cnt, bsum, rowp, cursor, dinv, NN);
    k_scatter<<<(NE + 255) / 256, 256, 0, stream>>>(srcp, dstp, cursor, col, val, dinv, NE);

    int gemm_grid = (NN + GROWS - 1) / GROWS;
    int agg_grid  = 8 * ((NN + AGG_NPB - 1) / AGG_NPB);   // 8 slices x 782 chunks
    int stat_grid = (NN + SROWS - 1) / SROWS;
    int ew_grid   = (NN * (DD / 4) + 255) / 256;

    // ---- layer 1 ----
    k_gemm<<<gemm_grid, 256, 0, stream>>>(x, W1, bufA, NN);
    k_agg<<<agg_grid, 256, 0, stream>>>(bufA, rowp, col, val, dinv, b1, bufB, NN);
    hipMemsetAsync(sums, 0, 256 * sizeof(float), stream);
    k_stats<<<stat_grid, 128, 0, stream>>>(bufB, sums, NN);
    k_bn<<<ew_grid, 256, 0, stream>>>(bufB, x, sums, g1, be1, bufC, NN);

    // ---- layer 2 ----
    k_gemm<<<gemm_grid, 256, 0, stream>>>(bufC, W2, bufA, NN);
    k_agg<<<agg_grid, 256, 0, stream>>>(bufA, rowp, col, val, dinv, b2, bufB, NN);
    hipMemsetAsync(sums, 0, 256 * sizeof(float), stream);
    k_stats<<<stat_grid, 128, 0, stream>>>(bufB, sums, NN);
    k_bn<<<ew_grid, 256, 0, stream>>>(bufB, bufC, sums, g2, be2, bufA, NN);

    // ---- attention + output ----
    k_att<<<ATT_BLOCKS, 256, 0, stream>>>(bufA, Wa, ba, evec, Z, NN);
    k_out<<<ew_grid, 256, 0, stream>>>(bufA, evec, Z, out, NN);
}

// Round 5
// 564.492 us; speedup vs baseline: 1.0304x; 1.0304x over previous
//
#include <hip/hip_runtime.h>

#define NN 50000
#define DD 128
#define NE 800000
#define BN_EPS 1e-5f

// ---------------- CSR build ----------------
__global__ void k_hist(const int* __restrict__ dst, int* __restrict__ cnt, int ne) {
    int i = blockIdx.x * blockDim.x + threadIdx.x;
    if (i < ne) atomicAdd(&cnt[dst[i]], 1);
}

// phase A: per-block sums of cnt (coalesced)
__global__ __launch_bounds__(256) void k_bsum(const int* __restrict__ cnt,
                                              int* __restrict__ bsum, int n) {
    __shared__ int red[256];
    int i = blockIdx.x * 256 + threadIdx.x;
    int v = (i < n) ? cnt[i] : 0;
    red[threadIdx.x] = v;
    __syncthreads();
    for (int off = 128; off > 0; off >>= 1) {
        if (threadIdx.x < off) red[threadIdx.x] += red[threadIdx.x + off];
        __syncthreads();
    }
    if (threadIdx.x == 0) bsum[blockIdx.x] = red[0];
}

// phase B: inclusive scan of block sums (nb <= 256) in one block
__global__ __launch_bounds__(256) void k_bscan(int* __restrict__ bsum, int nb) {
    __shared__ int sh[256];
    int t = threadIdx.x;
    sh[t] = (t < nb) ? bsum[t] : 0;
    __syncthreads();
    for (int off = 1; off < 256; off <<= 1) {
        int add = (t >= off) ? sh[t - off] : 0;
        __syncthreads();
        sh[t] += add;
        __syncthreads();
    }
    if (t < nb) bsum[t] = sh[t];
}

// phase C: per-block exclusive prefix + write rowp/cursor/dinv (coalesced)
__global__ __launch_bounds__(256) void k_rowp(const int* __restrict__ cnt,
                                              const int* __restrict__ bsum,
                                              int* __restrict__ rowp,
                                              int* __restrict__ cursor,
                                              float* __restrict__ dinv, int n) {
    __shared__ int sh[256];
    int t = threadIdx.x;
    int i = blockIdx.x * 256 + t;
    int v = (i < n) ? cnt[i] : 0;
    sh[t] = v;
    __syncthreads();
    for (int off = 1; off < 256; off <<= 1) {
        int add = (t >= off) ? sh[t - off] : 0;
        __syncthreads();
        sh[t] += add;
        __syncthreads();
    }
    int base = (blockIdx.x > 0) ? bsum[blockIdx.x - 1] : 0;
    int excl = base + sh[t] - v;
    if (i < n) {
        rowp[i] = excl;
        cursor[i] = excl;
        dinv[i] = 1.0f / sqrtf((float)(v + 1));
        if (i == n - 1) rowp[n] = excl + v;
    }
}

__global__ void k_scatter(const int* __restrict__ src, const int* __restrict__ dst,
                          int* __restrict__ cursor, int* __restrict__ col, int ne) {
    int i = blockIdx.x * blockDim.x + threadIdx.x;
    if (i < ne) {
        int d = dst[i], s = src[i];
        int pos = atomicAdd(&cursor[d], 1);
        col[pos] = s;
    }
}

// ---------------- GEMM: C_sliced = A[n,128] * W[128,128] ----------------
// Output written in slice-major layout: hs[slice][node][16], slice = f/16.
#define GROWS 32
__global__ __launch_bounds__(256) void k_gemm(const float* __restrict__ A,
                                              const float* __restrict__ W,
                                              float* __restrict__ C, int n) {
    __shared__ float sA[GROWS][DD];   // 16 KB
    __shared__ float sW[DD][DD];      // 64 KB
    int tid = threadIdx.x;
    int row0 = blockIdx.x * GROWS;

    {
        const float4* Wv = (const float4*)W;
        float4* sWv = (float4*)&sW[0][0];
        for (int i = tid; i < DD * DD / 4; i += 256) sWv[i] = Wv[i];
    }
    {
        const float4* Av = (const float4*)(A + (size_t)row0 * DD);
        float4* sAv = (float4*)&sA[0][0];
        for (int i = tid; i < GROWS * DD / 4; i += 256) {
            int r = i >> 5;
            float4 v = make_float4(0.f, 0.f, 0.f, 0.f);
            if (row0 + r < n) v = Av[i];
            sAv[i] = v;
        }
    }
    __syncthreads();

    int tx = tid & 31;
    int ty = tid >> 5;
    float acc[4][4] = {};
    for (int k = 0; k < DD; k += 4) {
        float a[4][4], b[4][4];
        #pragma unroll
        for (int r = 0; r < 4; r++)
            *(float4*)a[r] = *(const float4*)&sA[ty * 4 + r][k];
        #pragma unroll
        for (int kk = 0; kk < 4; kk++)
            *(float4*)b[kk] = *(const float4*)&sW[k + kk][tx * 4];
        #pragma unroll
        for (int r = 0; r < 4; r++)
            #pragma unroll
            for (int kk = 0; kk < 4; kk++)
                #pragma unroll
                for (int c = 0; c < 4; c++)
                    acc[r][c] += a[r][kk] * b[kk][c];
    }
    int slice = tx >> 2;          // feature f = tx*4 -> slice f/16
    int within = (tx & 3) * 4;    // offset inside the 16-float node block
    #pragma unroll
    for (int r = 0; r < 4; r++) {
        int row = row0 + ty * 4 + r;
        if (row < n)
            *(float4*)(C + (size_t)slice * NN * 16 + (size_t)row * 16 + within) =
                *(float4*)acc[r];
    }
}

// ---------------- aggregation: XCD-local slice-major gather + fused BN stats --------
// slice = blockIdx & 7 -> XCD-local 3.2 MB contiguous slab (fits 4 MB L2).
// 4 lanes x float4 = one 64 B node-block; 16 nodes per wave.
// Epilogue: LDS-reduce per-feature sum/sumsq over the block's 64 nodes,
// 32 atomics per block into sums[256] (replaces the k_stats pass).
#define AGG_NPB 64
__global__ __launch_bounds__(256) void k_agg(const float* __restrict__ hs,
                                             const int* __restrict__ rowp,
                                             const int* __restrict__ col,
                                             const float* __restrict__ dinv,
                                             const float* __restrict__ bias,
                                             float* __restrict__ out,
                                             float* __restrict__ sums, int n) {
    int slice = blockIdx.x & 7;
    int chunk = blockIdx.x >> 3;
    int tid = threadIdx.x;
    int grp = tid >> 2;          // node within chunk
    int sub = tid & 3;           // float4 within 64 B node block
    int node = chunk * AGG_NPB + grp;
    bool active = node < n;
    const float* base = hs + (size_t)slice * NN * 16;
    float4 o = make_float4(0.f, 0.f, 0.f, 0.f);
    if (active) {
        int beg = rowp[node], end = rowp[node + 1];
        float4 acc = make_float4(0.f, 0.f, 0.f, 0.f);
        #pragma unroll 4
        for (int e = beg; e < end; e++) {
            int s = __builtin_nontemporal_load(col + e);
            float w = dinv[s];
            float4 hv = *(const float4*)(base + (size_t)s * 16 + sub * 4);
            acc.x += w * hv.x;
            acc.y += w * hv.y;
            acc.z += w * hv.z;
            acc.w += w * hv.w;
        }
        float di = dinv[node];
        float dii = di * di;
        float4 hv = *(const float4*)(base + (size_t)node * 16 + sub * 4);
        float4 bv = *(const float4*)(bias + slice * 16 + sub * 4);
        o.x = di * acc.x + dii * hv.x + bv.x;
        o.y = di * acc.y + dii * hv.y + bv.y;
        o.z = di * acc.z + dii * hv.z + bv.z;
        o.w = di * acc.w + dii * hv.w + bv.w;
        *(float4*)(out + (size_t)node * DD + slice * 16 + sub * 4) = o;
    }
    // fused BN partial stats (inactive nodes contribute 0)
    __shared__ float4 red_s[256];
    __shared__ float4 red_q[256];
    red_s[tid] = o;
    red_q[tid] = make_float4(o.x * o.x, o.y * o.y, o.z * o.z, o.w * o.w);
    __syncthreads();
    #pragma unroll
    for (int off = 128; off >= 4; off >>= 1) {
        if (tid < off) {
            float4 a = red_s[tid + off], b = red_q[tid + off];
            red_s[tid].x += a.x; red_s[tid].y += a.y;
            red_s[tid].z += a.z; red_s[tid].w += a.w;
            red_q[tid].x += b.x; red_q[tid].y += b.y;
            red_q[tid].z += b.z; red_q[tid].w += b.w;
        }
        __syncthreads();
    }
    if (tid < 4) {
        float4 a = red_s[tid], b = red_q[tid];
        int f = slice * 16 + tid * 4;
        atomicAdd(&sums[f + 0], a.x);
        atomicAdd(&sums[f + 1], a.y);
        atomicAdd(&sums[f + 2], a.z);
        atomicAdd(&sums[f + 3], a.w);
        atomicAdd(&sums[DD + f + 0], b.x);
        atomicAdd(&sums[DD + f + 1], b.y);
        atomicAdd(&sums[DD + f + 2], b.z);
        atomicAdd(&sums[DD + f + 3], b.w);
    }
}

// ---------------- BN apply + ReLU + residual ----------------
__global__ __launch_bounds__(256) void k_bn(const float* __restrict__ X,
                                            const float* __restrict__ res,
                                            const float* __restrict__ sums,
                                            const float* __restrict__ gamma,
                                            const float* __restrict__ beta,
                                            float* __restrict__ out, int n) {
    int idx = blockIdx.x * blockDim.x + threadIdx.x;
    int total = n * (DD / 4);
    if (idx >= total) return;
    int f = (idx & 31) * 4;
    float4 v = ((const float4*)X)[idx];
    float4 rv = ((const float4*)res)[idx];
    float o[4];
    float vi[4] = {v.x, v.y, v.z, v.w};
    float ri[4] = {rv.x, rv.y, rv.z, rv.w};
    float inv_n = 1.0f / (float)n;
    #pragma unroll
    for (int j = 0; j < 4; j++) {
        float mean = sums[f + j] * inv_n;
        float var = sums[DD + f + j] * inv_n - mean * mean;
        float x = (vi[j] - mean) * (1.0f / sqrtf(var + BN_EPS)) * gamma[f + j] + beta[f + j];
        x = fmaxf(x, 0.f);
        o[j] = x + ri[j];
    }
    ((float4*)out)[idx] = make_float4(o[0], o[1], o[2], o[3]);
}

// ---------------- attention: grid-stride waves, one atomic per block ----------------
#define ATT_BLOCKS 256
__global__ __launch_bounds__(256) void k_att(const float* __restrict__ H,
                                             const float* __restrict__ Wa,
                                             const float* __restrict__ ba,
                                             float* __restrict__ evec,
                                             float* __restrict__ Z, int n) {
    int wave = threadIdx.x >> 6;
    int lane = threadIdx.x & 63;
    int gw = blockIdx.x * 4 + wave;
    int nw = gridDim.x * 4;
    float2 wv = *(const float2*)(Wa + lane * 2);
    float bb = ba[0];
    float lsum = 0.f;
    for (int node = gw; node < n; node += nw) {
        float2 hv = *(const float2*)(H + (size_t)node * DD + lane * 2);
        float t = hv.x * wv.x + hv.y * wv.y;
        #pragma unroll
        for (int off = 1; off < 64; off <<= 1) t += __shfl_xor(t, off);
        float ev = expf(tanhf(t + bb));
        if (lane == 0) {
            evec[node] = ev;
            lsum += ev;
        }
    }
    __shared__ float part[4];
    if (lane == 0) part[wave] = lsum;
    __syncthreads();
    if (threadIdx.x == 0)
        atomicAdd(Z, part[0] + part[1] + part[2] + part[3]);
}

// ---------------- final: out = h * e / Z ----------------
__global__ __launch_bounds__(256) void k_out(const float* __restrict__ H,
                                             const float* __restrict__ evec,
                                             const float* __restrict__ Z,
                                             float* __restrict__ out, int n) {
    int idx = blockIdx.x * blockDim.x + threadIdx.x;
    int total = n * (DD / 4);
    if (idx >= total) return;
    int node = idx >> 5;
    float s = evec[node] / Z[0];
    float4 h = ((const float4*)H)[idx];
    ((float4*)out)[idx] = make_float4(h.x * s, h.y * s, h.z * s, h.w * s);
}

extern "C" void kernel_launch(void* const* d_in, const int* in_sizes, int n_in,
                              void* d_out, int out_size, void* d_ws, size_t ws_size,
                              hipStream_t stream) {
    const float* x   = (const float*)d_in[0];
    const int* eidx  = (const int*)d_in[1];
    const float* W1  = (const float*)d_in[2];
    const float* b1  = (const float*)d_in[3];
    const float* g1  = (const float*)d_in[4];
    const float* be1 = (const float*)d_in[5];
    const float* W2  = (const float*)d_in[6];
    const float* b2  = (const float*)d_in[7];
    const float* g2  = (const float*)d_in[8];
    const float* be2 = (const float*)d_in[9];
    const float* Wa  = (const float*)d_in[10];
    const float* ba  = (const float*)d_in[11];
    float* out = (float*)d_out;

    const int* srcp = eidx;
    const int* dstp = eidx + NE;

    float* bufA = (float*)d_ws;              // N*D (sliced GEMM out / final h)
    float* bufB = bufA + (size_t)NN * DD;    // N*D (agg out)
    float* bufC = bufB + (size_t)NN * DD;    // N*D (layer-1 out)
    float* dinv = bufC + (size_t)NN * DD;    // NN
    float* evec = dinv + NN;                 // NN
    float* sums = evec + NN;                 // 512 (two layer regions)
    float* Z    = sums + 512;                // 1 (pad 64)
    int* cnt    = (int*)(Z + 64);            // NN
    int* rowp   = cnt + NN;                  // NN+1 (pad 64)
    int* cursor = rowp + NN + 64;            // NN
    int* col    = cursor + NN;               // NE
    int* bsum   = col + NE;                  // 256

    float* sumsL1 = sums;
    float* sumsL2 = sums + 256;

    const int nscan = (NN + 255) / 256;      // 196 blocks

    // ---- CSR build ----
    hipMemsetAsync(cnt, 0, (size_t)NN * sizeof(int), stream);
    hipMemsetAsync(Z, 0, sizeof(float), stream);
    hipMemsetAsync(sums, 0, 512 * sizeof(float), stream);
    k_hist<<<(NE + 255) / 256, 256, 0, stream>>>(dstp, cnt, NE);
    k_bsum<<<nscan, 256, 0, stream>>>(cnt, bsum, NN);
    k_bscan<<<1, 256, 0, stream>>>(bsum, nscan);
    k_rowp<<<nscan, 256, 0, stream>>>(cnt, bsum, rowp, cursor, dinv, NN);
    k_scatter<<<(NE + 255) / 256, 256, 0, stream>>>(srcp, dstp, cursor, col, NE);

    int gemm_grid = (NN + GROWS - 1) / GROWS;
    int agg_grid  = 8 * ((NN + AGG_NPB - 1) / AGG_NPB);   // 8 slices x 782 chunks
    int ew_grid   = (NN * (DD / 4) + 255) / 256;

    // ---- layer 1 ----
    k_gemm<<<gemm_grid, 256, 0, stream>>>(x, W1, bufA, NN);
    k_agg<<<agg_grid, 256, 0, stream>>>(bufA, rowp, col, dinv, b1, bufB, sumsL1, NN);
    k_bn<<<ew_grid, 256, 0, stream>>>(bufB, x, sumsL1, g1, be1, bufC, NN);

    // ---- layer 2 ----
    k_gemm<<<gemm_grid, 256, 0, stream>>>(bufC, W2, bufA, NN);
    k_agg<<<agg_grid, 256, 0, stream>>>(bufA, rowp, col, dinv, b2, bufB, sumsL2, NN);
    k_bn<<<ew_grid, 256, 0, stream>>>(bufB, bufC, sumsL2, g2, be2, bufA, NN);

    // ---- attention + output ----
    k_att<<<ATT_BLOCKS, 256, 0, stream>>>(bufA, Wa, ba, evec, Z, NN);
    k_out<<<ew_grid, 256, 0, stream>>>(bufA, evec, Z, out, NN);
}

// Round 6
// 450.172 us; speedup vs baseline: 1.2921x; 1.2539x over previous
//
#include <hip/hip_runtime.h>

#define NN 50000
#define DD 128
#define NE 800000
#define BN_EPS 1e-5f

// ---------------- CSR build ----------------
__global__ void k_hist(const int* __restrict__ dst, int* __restrict__ cnt, int ne) {
    int i = blockIdx.x * blockDim.x + threadIdx.x;
    if (i < ne) atomicAdd(&cnt[dst[i]], 1);
}

// phase A: per-block sums of cnt (coalesced)
__global__ __launch_bounds__(256) void k_bsum(const int* __restrict__ cnt,
                                              int* __restrict__ bsum, int n) {
    __shared__ int red[256];
    int i = blockIdx.x * 256 + threadIdx.x;
    int v = (i < n) ? cnt[i] : 0;
    red[threadIdx.x] = v;
    __syncthreads();
    for (int off = 128; off > 0; off >>= 1) {
        if (threadIdx.x < off) red[threadIdx.x] += red[threadIdx.x + off];
        __syncthreads();
    }
    if (threadIdx.x == 0) bsum[blockIdx.x] = red[0];
}

// phase B: inclusive scan of block sums (nb <= 256) in one block
__global__ __launch_bounds__(256) void k_bscan(int* __restrict__ bsum, int nb) {
    __shared__ int sh[256];
    int t = threadIdx.x;
    sh[t] = (t < nb) ? bsum[t] : 0;
    __syncthreads();
    for (int off = 1; off < 256; off <<= 1) {
        int add = (t >= off) ? sh[t - off] : 0;
        __syncthreads();
        sh[t] += add;
        __syncthreads();
    }
    if (t < nb) bsum[t] = sh[t];
}

// phase C: per-block exclusive prefix + write rowp/cursor/dinv (coalesced)
__global__ __launch_bounds__(256) void k_rowp(const int* __restrict__ cnt,
                                              const int* __restrict__ bsum,
                                              int* __restrict__ rowp,
                                              int* __restrict__ cursor,
                                              float* __restrict__ dinv, int n) {
    __shared__ int sh[256];
    int t = threadIdx.x;
    int i = blockIdx.x * 256 + t;
    int v = (i < n) ? cnt[i] : 0;
    sh[t] = v;
    __syncthreads();
    for (int off = 1; off < 256; off <<= 1) {
        int add = (t >= off) ? sh[t - off] : 0;
        __syncthreads();
        sh[t] += add;
        __syncthreads();
    }
    int base = (blockIdx.x > 0) ? bsum[blockIdx.x - 1] : 0;
    int excl = base + sh[t] - v;
    if (i < n) {
        rowp[i] = excl;
        cursor[i] = excl;
        dinv[i] = 1.0f / sqrtf((float)(v + 1));
        if (i == n - 1) rowp[n] = excl + v;
    }
}

__global__ void k_scatter(const int* __restrict__ src, const int* __restrict__ dst,
                          int* __restrict__ cursor, int* __restrict__ col,
                          float* __restrict__ val, const float* __restrict__ dinv,
                          int ne) {
    int i = blockIdx.x * blockDim.x + threadIdx.x;
    if (i < ne) {
        int d = dst[i], s = src[i];
        int pos = atomicAdd(&cursor[d], 1);
        col[pos] = s;
        val[pos] = dinv[s];
    }
}

// ---------------- GEMM: C[n,128] = A[n,128] * W[128,128] (row-major out) ----------------
#define GROWS 32
__global__ __launch_bounds__(256) void k_gemm(const float* __restrict__ A,
                                              const float* __restrict__ W,
                                              float* __restrict__ C, int n) {
    __shared__ float sA[GROWS][DD];   // 16 KB
    __shared__ float sW[DD][DD];      // 64 KB
    int tid = threadIdx.x;
    int row0 = blockIdx.x * GROWS;

    {
        const float4* Wv = (const float4*)W;
        float4* sWv = (float4*)&sW[0][0];
        for (int i = tid; i < DD * DD / 4; i += 256) sWv[i] = Wv[i];
    }
    {
        const float4* Av = (const float4*)(A + (size_t)row0 * DD);
        float4* sAv = (float4*)&sA[0][0];
        for (int i = tid; i < GROWS * DD / 4; i += 256) {
            int r = i >> 5;
            float4 v = make_float4(0.f, 0.f, 0.f, 0.f);
            if (row0 + r < n) v = Av[i];
            sAv[i] = v;
        }
    }
    __syncthreads();

    int tx = tid & 31;
    int ty = tid >> 5;
    float acc[4][4] = {};
    for (int k = 0; k < DD; k += 4) {
        float a[4][4], b[4][4];
        #pragma unroll
        for (int r = 0; r < 4; r++)
            *(float4*)a[r] = *(const float4*)&sA[ty * 4 + r][k];
        #pragma unroll
        for (int kk = 0; kk < 4; kk++)
            *(float4*)b[kk] = *(const float4*)&sW[k + kk][tx * 4];
        #pragma unroll
        for (int r = 0; r < 4; r++)
            #pragma unroll
            for (int kk = 0; kk < 4; kk++)
                #pragma unroll
                for (int c = 0; c < 4; c++)
                    acc[r][c] += a[r][kk] * b[kk][c];
    }
    #pragma unroll
    for (int r = 0; r < 4; r++) {
        int row = row0 + ty * 4 + r;
        if (row < n)
            *(float4*)(C + (size_t)row * DD + tx * 4) = *(float4*)acc[r];
    }
}

// ---------------- aggregation: 16 lanes/node, full-row gather, fused BN stats --------
// 16 lanes x 2 float4 = one 512 B row per edge (2 wave-instrs, 4 L2 lines).
// 4 nodes/wave x unroll 4 = up to 32 outstanding gathers per wave.
// Epilogue: shfl-reduce over the wave's 4 nodes, LDS-combine 4 waves,
// 256 atomics/block into 8-way banked sums (bank = blockIdx & 7).
#define AGG_NPB 16   // nodes per block (256 thr / 16 lanes-per-node)
__global__ __launch_bounds__(256) void k_agg(const float* __restrict__ h,
                                             const int* __restrict__ rowp,
                                             const int* __restrict__ col,
                                             const float* __restrict__ val,
                                             const float* __restrict__ dinv,
                                             const float* __restrict__ bias,
                                             float* __restrict__ out,
                                             float* __restrict__ sums, int n) {
    int tid = threadIdx.x;
    int grp = tid >> 4;            // node within block (0..15)
    int sub = tid & 15;            // lane within node
    int node = blockIdx.x * AGG_NPB + grp;
    bool active = node < n;
    int f = sub * 8;               // features f..f+7

    float4 a0 = make_float4(0.f, 0.f, 0.f, 0.f);
    float4 a1 = make_float4(0.f, 0.f, 0.f, 0.f);
    int beg = 0, end = 0;
    if (active) { beg = rowp[node]; end = rowp[node + 1]; }
    #pragma unroll 4
    for (int e = beg; e < end; e++) {
        int s = col[e];
        float w = val[e];
        const float* hp = h + (size_t)s * DD + f;
        float4 v0 = *(const float4*)hp;
        float4 v1 = *(const float4*)(hp + 4);
        a0.x += w * v0.x; a0.y += w * v0.y; a0.z += w * v0.z; a0.w += w * v0.w;
        a1.x += w * v1.x; a1.y += w * v1.y; a1.z += w * v1.z; a1.w += w * v1.w;
    }
    float4 o0 = make_float4(0.f, 0.f, 0.f, 0.f);
    float4 o1 = make_float4(0.f, 0.f, 0.f, 0.f);
    if (active) {
        float di = dinv[node], dii = di * di;
        const float* hp = h + (size_t)node * DD + f;
        float4 s0 = *(const float4*)hp;
        float4 s1 = *(const float4*)(hp + 4);
        float4 b0 = *(const float4*)(bias + f);
        float4 b1 = *(const float4*)(bias + f + 4);
        o0.x = di * a0.x + dii * s0.x + b0.x;
        o0.y = di * a0.y + dii * s0.y + b0.y;
        o0.z = di * a0.z + dii * s0.z + b0.z;
        o0.w = di * a0.w + dii * s0.w + b0.w;
        o1.x = di * a1.x + dii * s1.x + b1.x;
        o1.y = di * a1.y + dii * s1.y + b1.y;
        o1.z = di * a1.z + dii * s1.z + b1.z;
        o1.w = di * a1.w + dii * s1.w + b1.w;
        float* op = out + (size_t)node * DD + f;
        *(float4*)op = o0;
        *(float4*)(op + 4) = o1;
    }
    // fused BN stats: sum & sumsq per feature
    float4 q0 = make_float4(o0.x * o0.x, o0.y * o0.y, o0.z * o0.z, o0.w * o0.w);
    float4 q1 = make_float4(o1.x * o1.x, o1.y * o1.y, o1.z * o1.z, o1.w * o1.w);
    // reduce across the wave's 4 node-groups (lane bits 4,5)
    #pragma unroll
    for (int m = 16; m <= 32; m <<= 1) {
        o0.x += __shfl_xor(o0.x, m); o0.y += __shfl_xor(o0.y, m);
        o0.z += __shfl_xor(o0.z, m); o0.w += __shfl_xor(o0.w, m);
        o1.x += __shfl_xor(o1.x, m); o1.y += __shfl_xor(o1.y, m);
        o1.z += __shfl_xor(o1.z, m); o1.w += __shfl_xor(o1.w, m);
        q0.x += __shfl_xor(q0.x, m); q0.y += __shfl_xor(q0.y, m);
        q0.z += __shfl_xor(q0.z, m); q0.w += __shfl_xor(q0.w, m);
        q1.x += __shfl_xor(q1.x, m); q1.y += __shfl_xor(q1.y, m);
        q1.z += __shfl_xor(q1.z, m); q1.w += __shfl_xor(q1.w, m);
    }
    __shared__ float rs[4][128];
    __shared__ float rq[4][128];
    int w = tid >> 6;
    int lane = tid & 63;
    if (lane < 16) {
        int fb = lane * 8;
        rs[w][fb + 0] = o0.x; rs[w][fb + 1] = o0.y;
        rs[w][fb + 2] = o0.z; rs[w][fb + 3] = o0.w;
        rs[w][fb + 4] = o1.x; rs[w][fb + 5] = o1.y;
        rs[w][fb + 6] = o1.z; rs[w][fb + 7] = o1.w;
        rq[w][fb + 0] = q0.x; rq[w][fb + 1] = q0.y;
        rq[w][fb + 2] = q0.z; rq[w][fb + 3] = q0.w;
        rq[w][fb + 4] = q1.x; rq[w][fb + 5] = q1.y;
        rq[w][fb + 6] = q1.z; rq[w][fb + 7] = q1.w;
    }
    __syncthreads();
    int bank = blockIdx.x & 7;
    if (tid < 128) {
        float s = rs[0][tid] + rs[1][tid] + rs[2][tid] + rs[3][tid];
        atomicAdd(&sums[bank * 256 + tid], s);
    } else {
        int t = tid - 128;
        float q = rq[0][t] + rq[1][t] + rq[2][t] + rq[3][t];
        atomicAdd(&sums[bank * 256 + 128 + t], q);
    }
}

// ---------------- BN apply + ReLU + residual (reads 8-banked sums) ----------------
__global__ __launch_bounds__(256) void k_bn(const float* __restrict__ X,
                                            const float* __restrict__ res,
                                            const float* __restrict__ sums,
                                            const float* __restrict__ gamma,
                                            const float* __restrict__ beta,
                                            float* __restrict__ out, int n) {
    __shared__ float s_scale[128], s_shift[128];
    if (threadIdx.x < 128) {
        int ff = threadIdx.x;
        float ssum = 0.f, qsum = 0.f;
        #pragma unroll
        for (int b = 0; b < 8; b++) {
            ssum += sums[b * 256 + ff];
            qsum += sums[b * 256 + 128 + ff];
        }
        float inv_n = 1.0f / (float)n;
        float mean = ssum * inv_n;
        float var = qsum * inv_n - mean * mean;
        float sc = gamma[ff] * (1.0f / sqrtf(var + BN_EPS));
        s_scale[ff] = sc;
        s_shift[ff] = beta[ff] - mean * sc;
    }
    __syncthreads();
    int idx = blockIdx.x * blockDim.x + threadIdx.x;
    int total = n * (DD / 4);
    if (idx >= total) return;
    int f = (idx & 31) * 4;
    float4 v = ((const float4*)X)[idx];
    float4 rv = ((const float4*)res)[idx];
    float vi[4] = {v.x, v.y, v.z, v.w};
    float ri[4] = {rv.x, rv.y, rv.z, rv.w};
    float o[4];
    #pragma unroll
    for (int j = 0; j < 4; j++) {
        float x = vi[j] * s_scale[f + j] + s_shift[f + j];
        x = fmaxf(x, 0.f);
        o[j] = x + ri[j];
    }
    ((float4*)out)[idx] = make_float4(o[0], o[1], o[2], o[3]);
}

// ---------------- attention: grid-stride waves, one atomic per block ----------------
#define ATT_BLOCKS 256
__global__ __launch_bounds__(256) void k_att(const float* __restrict__ H,
                                             const float* __restrict__ Wa,
                                             const float* __restrict__ ba,
                                             float* __restrict__ evec,
                                             float* __restrict__ Z, int n) {
    int wave = threadIdx.x >> 6;
    int lane = threadIdx.x & 63;
    int gw = blockIdx.x * 4 + wave;
    int nw = gridDim.x * 4;
    float2 wv = *(const float2*)(Wa + lane * 2);
    float bb = ba[0];
    float lsum = 0.f;
    for (int node = gw; node < n; node += nw) {
        float2 hv = *(const float2*)(H + (size_t)node * DD + lane * 2);
        float t = hv.x * wv.x + hv.y * wv.y;
        #pragma unroll
        for (int off = 1; off < 64; off <<= 1) t += __shfl_xor(t, off);
        float ev = expf(tanhf(t + bb));
        if (lane == 0) {
            evec[node] = ev;
            lsum += ev;
        }
    }
    __shared__ float part[4];
    if (lane == 0) part[wave] = lsum;
    __syncthreads();
    if (threadIdx.x == 0)
        atomicAdd(Z, part[0] + part[1] + part[2] + part[3]);
}

// ---------------- final: out = h * e / Z ----------------
__global__ __launch_bounds__(256) void k_out(const float* __restrict__ H,
                                             const float* __restrict__ evec,
                                             const float* __restrict__ Z,
                                             float* __restrict__ out, int n) {
    int idx = blockIdx.x * blockDim.x + threadIdx.x;
    int total = n * (DD / 4);
    if (idx >= total) return;
    int node = idx >> 5;
    float s = evec[node] / Z[0];
    float4 h = ((const float4*)H)[idx];
    ((float4*)out)[idx] = make_float4(h.x * s, h.y * s, h.z * s, h.w * s);
}

extern "C" void kernel_launch(void* const* d_in, const int* in_sizes, int n_in,
                              void* d_out, int out_size, void* d_ws, size_t ws_size,
                              hipStream_t stream) {
    const float* x   = (const float*)d_in[0];
    const int* eidx  = (const int*)d_in[1];
    const float* W1  = (const float*)d_in[2];
    const float* b1  = (const float*)d_in[3];
    const float* g1  = (const float*)d_in[4];
    const float* be1 = (const float*)d_in[5];
    const float* W2  = (const float*)d_in[6];
    const float* b2  = (const float*)d_in[7];
    const float* g2  = (const float*)d_in[8];
    const float* be2 = (const float*)d_in[9];
    const float* Wa  = (const float*)d_in[10];
    const float* ba  = (const float*)d_in[11];
    float* out = (float*)d_out;

    const int* srcp = eidx;
    const int* dstp = eidx + NE;

    float* bufA = (float*)d_ws;              // N*D
    float* bufB = bufA + (size_t)NN * DD;    // N*D
    float* bufC = bufB + (size_t)NN * DD;    // N*D
    float* val  = bufC + (size_t)NN * DD;    // NE
    float* dinv = val + NE;                  // NN
    float* evec = dinv + NN;                 // NN
    float* sums = evec + NN;                 // 2 layers x 8 banks x 256 = 4096
    float* Z    = sums + 4096;               // 1 (pad 64)
    int* cnt    = (int*)(Z + 64);            // NN
    int* rowp   = cnt + NN;                  // NN+1 (pad 64)
    int* cursor = rowp + NN + 64;            // NN
    int* col    = cursor + NN;               // NE
    int* bsum   = col + NE;                  // 256

    float* sumsL1 = sums;
    float* sumsL2 = sums + 2048;

    const int nscan = (NN + 255) / 256;      // 196 blocks

    // ---- CSR build ----
    hipMemsetAsync(cnt, 0, (size_t)NN * sizeof(int), stream);
    hipMemsetAsync(Z, 0, sizeof(float), stream);
    hipMemsetAsync(sums, 0, 4096 * sizeof(float), stream);
    k_hist<<<(NE + 255) / 256, 256, 0, stream>>>(dstp, cnt, NE);
    k_bsum<<<nscan, 256, 0, stream>>>(cnt, bsum, NN);
    k_bscan<<<1, 256, 0, stream>>>(bsum, nscan);
    k_rowp<<<nscan, 256, 0, stream>>>(cnt, bsum, rowp, cursor, dinv, NN);
    k_scatter<<<(NE + 255) / 256, 256, 0, stream>>>(srcp, dstp, cursor, col, val, dinv, NE);

    int gemm_grid = (NN + GROWS - 1) / GROWS;
    int agg_grid  = (NN + AGG_NPB - 1) / AGG_NPB;   // 3125
    int ew_grid   = (NN * (DD / 4) + 255) / 256;

    // ---- layer 1 ----
    k_gemm<<<gemm_grid, 256, 0, stream>>>(x, W1, bufA, NN);
    k_agg<<<agg_grid, 256, 0, stream>>>(bufA, rowp, col, val, dinv, b1, bufB, sumsL1, NN);
    k_bn<<<ew_grid, 256, 0, stream>>>(bufB, x, sumsL1, g1, be1, bufC, NN);

    // ---- layer 2 ----
    k_gemm<<<gemm_grid, 256, 0, stream>>>(bufC, W2, bufA, NN);
    k_agg<<<agg_grid, 256, 0, stream>>>(bufA, rowp, col, val, dinv, b2, bufB, sumsL2, NN);
    k_bn<<<ew_grid, 256, 0, stream>>>(bufB, bufC, sumsL2, g2, be2, bufA, NN);

    // ---- attention + output ----
    k_att<<<ATT_BLOCKS, 256, 0, stream>>>(bufA, Wa, ba, evec, Z, NN);
    k_out<<<ew_grid, 256, 0, stream>>>(bufA, evec, Z, out, NN);
}

// Round 7
// 438.864 us; speedup vs baseline: 1.3254x; 1.0258x over previous
//
#include <hip/hip_runtime.h>

#define NN 50000
#define DD 128
#define NE 800000
#define BN_EPS 1e-5f

// ---------------- CSR build ----------------
__global__ void k_hist(const int* __restrict__ dst, int* __restrict__ cnt, int ne) {
    int i = blockIdx.x * blockDim.x + threadIdx.x;
    if (i < ne) atomicAdd(&cnt[dst[i]], 1);
}

// phase A: per-block sums of cnt (coalesced)
__global__ __launch_bounds__(256) void k_bsum(const int* __restrict__ cnt,
                                              int* __restrict__ bsum, int n) {
    __shared__ int red[256];
    int i = blockIdx.x * 256 + threadIdx.x;
    int v = (i < n) ? cnt[i] : 0;
    red[threadIdx.x] = v;
    __syncthreads();
    for (int off = 128; off > 0; off >>= 1) {
        if (threadIdx.x < off) red[threadIdx.x] += red[threadIdx.x + off];
        __syncthreads();
    }
    if (threadIdx.x == 0) bsum[blockIdx.x] = red[0];
}

// phase B: inclusive scan of block sums (nb <= 256) in one block
__global__ __launch_bounds__(256) void k_bscan(int* __restrict__ bsum, int nb) {
    __shared__ int sh[256];
    int t = threadIdx.x;
    sh[t] = (t < nb) ? bsum[t] : 0;
    __syncthreads();
    for (int off = 1; off < 256; off <<= 1) {
        int add = (t >= off) ? sh[t - off] : 0;
        __syncthreads();
        sh[t] += add;
        __syncthreads();
    }
    if (t < nb) bsum[t] = sh[t];
}

// phase C: per-block exclusive prefix + write rowp/cursor/dinv (coalesced)
// block 0 also zeroes sums/Z (consumed later in stream order).
__global__ __launch_bounds__(256) void k_rowp(const int* __restrict__ cnt,
                                              const int* __restrict__ bsum,
                                              int* __restrict__ rowp,
                                              int* __restrict__ cursor,
                                              float* __restrict__ dinv,
                                              float* __restrict__ sumsZ, int n) {
    if (blockIdx.x == 0) {
        for (int i = threadIdx.x; i < 4160; i += 256) sumsZ[i] = 0.f;
    }
    __shared__ int sh[256];
    int t = threadIdx.x;
    int i = blockIdx.x * 256 + t;
    int v = (i < n) ? cnt[i] : 0;
    sh[t] = v;
    __syncthreads();
    for (int off = 1; off < 256; off <<= 1) {
        int add = (t >= off) ? sh[t - off] : 0;
        __syncthreads();
        sh[t] += add;
        __syncthreads();
    }
    int base = (blockIdx.x > 0) ? bsum[blockIdx.x - 1] : 0;
    int excl = base + sh[t] - v;
    if (i < n) {
        rowp[i] = excl;
        cursor[i] = excl;
        dinv[i] = 1.0f / sqrtf((float)(v + 1));
        if (i == n - 1) rowp[n] = excl + v;
    }
}

__global__ void k_scatter(const int* __restrict__ src, const int* __restrict__ dst,
                          int* __restrict__ cursor, int* __restrict__ col,
                          float* __restrict__ val, const float* __restrict__ dinv,
                          int ne) {
    int i = blockIdx.x * blockDim.x + threadIdx.x;
    if (i < ne) {
        int d = dst[i], s = src[i];
        int pos = atomicAdd(&cursor[d], 1);
        col[pos] = s;
        val[pos] = dinv[s];
    }
}

// ---------------- GEMM: persistent blocks, W staged once per block ----------------
#define GROWS 32
#define GEMM_BLOCKS 512   // 2 blocks/CU co-resident (80 KB LDS each)
__global__ __launch_bounds__(256) void k_gemm(const float* __restrict__ A,
                                              const float* __restrict__ W,
                                              float* __restrict__ C, int n) {
    __shared__ float sA[GROWS][DD];   // 16 KB
    __shared__ float sW[DD][DD];      // 64 KB
    int tid = threadIdx.x;

    {
        const float4* Wv = (const float4*)W;
        float4* sWv = (float4*)&sW[0][0];
        for (int i = tid; i < DD * DD / 4; i += 256) sWv[i] = Wv[i];
    }

    int ntiles = (n + GROWS - 1) / GROWS;
    int tx = tid & 31;
    int ty = tid >> 5;
    for (int t = blockIdx.x; t < ntiles; t += gridDim.x) {
        int row0 = t * GROWS;
        __syncthreads();   // previous-iter readers done (also covers W stage, iter 0)
        {
            const float4* Av = (const float4*)(A + (size_t)row0 * DD);
            float4* sAv = (float4*)&sA[0][0];
            for (int i = tid; i < GROWS * DD / 4; i += 256) {
                int r = i >> 5;
                float4 v = make_float4(0.f, 0.f, 0.f, 0.f);
                if (row0 + r < n) v = Av[i];
                sAv[i] = v;
            }
        }
        __syncthreads();

        float acc[4][4] = {};
        for (int k = 0; k < DD; k += 4) {
            float a[4][4], b[4][4];
            #pragma unroll
            for (int r = 0; r < 4; r++)
                *(float4*)a[r] = *(const float4*)&sA[ty * 4 + r][k];
            #pragma unroll
            for (int kk = 0; kk < 4; kk++)
                *(float4*)b[kk] = *(const float4*)&sW[k + kk][tx * 4];
            #pragma unroll
            for (int r = 0; r < 4; r++)
                #pragma unroll
                for (int kk = 0; kk < 4; kk++)
                    #pragma unroll
                    for (int c = 0; c < 4; c++)
                        acc[r][c] += a[r][kk] * b[kk][c];
        }
        #pragma unroll
        for (int r = 0; r < 4; r++) {
            int row = row0 + ty * 4 + r;
            if (row < n)
                *(float4*)(C + (size_t)row * DD + tx * 4) = *(float4*)acc[r];
        }
    }
}

// ---------------- aggregation: 16 lanes/node, contiguous 256B loads, fused BN stats ----
// Lane sub reads features [sub*4, sub*4+4) and [64+sub*4, 64+sub*4+4):
// each load instruction covers a contiguous 256 B (2 lines); 4 lines/edge total.
#define AGG_NPB 16
__global__ __launch_bounds__(256) void k_agg(const float* __restrict__ h,
                                             const int* __restrict__ rowp,
                                             const int* __restrict__ col,
                                             const float* __restrict__ val,
                                             const float* __restrict__ dinv,
                                             const float* __restrict__ bias,
                                             float* __restrict__ out,
                                             float* __restrict__ sums, int n) {
    int tid = threadIdx.x;
    int grp = tid >> 4;            // node within block (0..15)
    int sub = tid & 15;            // lane within node
    int node = blockIdx.x * AGG_NPB + grp;
    bool active = node < n;
    int f0 = sub * 4;              // first 256 B half
    int f1 = 64 + sub * 4;         // second 256 B half

    float4 a0 = make_float4(0.f, 0.f, 0.f, 0.f);
    float4 a1 = make_float4(0.f, 0.f, 0.f, 0.f);
    int beg = 0, end = 0;
    if (active) { beg = rowp[node]; end = rowp[node + 1]; }
    #pragma unroll 4
    for (int e = beg; e < end; e++) {
        int s = col[e];
        float w = val[e];
        const float* hp = h + (size_t)s * DD;
        float4 v0 = *(const float4*)(hp + f0);
        float4 v1 = *(const float4*)(hp + f1);
        a0.x += w * v0.x; a0.y += w * v0.y; a0.z += w * v0.z; a0.w += w * v0.w;
        a1.x += w * v1.x; a1.y += w * v1.y; a1.z += w * v1.z; a1.w += w * v1.w;
    }
    float4 o0 = make_float4(0.f, 0.f, 0.f, 0.f);
    float4 o1 = make_float4(0.f, 0.f, 0.f, 0.f);
    if (active) {
        float di = dinv[node], dii = di * di;
        const float* hp = h + (size_t)node * DD;
        float4 s0 = *(const float4*)(hp + f0);
        float4 s1 = *(const float4*)(hp + f1);
        float4 b0 = *(const float4*)(bias + f0);
        float4 b1 = *(const float4*)(bias + f1);
        o0.x = di * a0.x + dii * s0.x + b0.x;
        o0.y = di * a0.y + dii * s0.y + b0.y;
        o0.z = di * a0.z + dii * s0.z + b0.z;
        o0.w = di * a0.w + dii * s0.w + b0.w;
        o1.x = di * a1.x + dii * s1.x + b1.x;
        o1.y = di * a1.y + dii * s1.y + b1.y;
        o1.z = di * a1.z + dii * s1.z + b1.z;
        o1.w = di * a1.w + dii * s1.w + b1.w;
        float* op = out + (size_t)node * DD;
        *(float4*)(op + f0) = o0;
        *(float4*)(op + f1) = o1;
    }
    // fused BN stats: sum & sumsq per feature
    float4 q0 = make_float4(o0.x * o0.x, o0.y * o0.y, o0.z * o0.z, o0.w * o0.w);
    float4 q1 = make_float4(o1.x * o1.x, o1.y * o1.y, o1.z * o1.z, o1.w * o1.w);
    #pragma unroll
    for (int m = 16; m <= 32; m <<= 1) {
        o0.x += __shfl_xor(o0.x, m); o0.y += __shfl_xor(o0.y, m);
        o0.z += __shfl_xor(o0.z, m); o0.w += __shfl_xor(o0.w, m);
        o1.x += __shfl_xor(o1.x, m); o1.y += __shfl_xor(o1.y, m);
        o1.z += __shfl_xor(o1.z, m); o1.w += __shfl_xor(o1.w, m);
        q0.x += __shfl_xor(q0.x, m); q0.y += __shfl_xor(q0.y, m);
        q0.z += __shfl_xor(q0.z, m); q0.w += __shfl_xor(q0.w, m);
        q1.x += __shfl_xor(q1.x, m); q1.y += __shfl_xor(q1.y, m);
        q1.z += __shfl_xor(q1.z, m); q1.w += __shfl_xor(q1.w, m);
    }
    __shared__ float rs[4][128];
    __shared__ float rq[4][128];
    int w = tid >> 6;
    int lane = tid & 63;
    if (lane < 16) {
        int fb = lane * 4;  // lane<16 -> sub==lane
        rs[w][fb + 0] = o0.x; rs[w][fb + 1] = o0.y;
        rs[w][fb + 2] = o0.z; rs[w][fb + 3] = o0.w;
        rs[w][64 + fb + 0] = o1.x; rs[w][64 + fb + 1] = o1.y;
        rs[w][64 + fb + 2] = o1.z; rs[w][64 + fb + 3] = o1.w;
        rq[w][fb + 0] = q0.x; rq[w][fb + 1] = q0.y;
        rq[w][fb + 2] = q0.z; rq[w][fb + 3] = q0.w;
        rq[w][64 + fb + 0] = q1.x; rq[w][64 + fb + 1] = q1.y;
        rq[w][64 + fb + 2] = q1.z; rq[w][64 + fb + 3] = q1.w;
    }
    __syncthreads();
    int bank = blockIdx.x & 7;
    if (tid < 128) {
        float s = rs[0][tid] + rs[1][tid] + rs[2][tid] + rs[3][tid];
        atomicAdd(&sums[bank * 256 + tid], s);
    } else {
        int t = tid - 128;
        float q = rq[0][t] + rq[1][t] + rq[2][t] + rq[3][t];
        atomicAdd(&sums[bank * 256 + 128 + t], q);
    }
}

// ---------------- BN apply + ReLU + residual (reads 8-banked sums) ----------------
__global__ __launch_bounds__(256) void k_bn(const float* __restrict__ X,
                                            const float* __restrict__ res,
                                            const float* __restrict__ sums,
                                            const float* __restrict__ gamma,
                                            const float* __restrict__ beta,
                                            float* __restrict__ out, int n) {
    __shared__ float s_scale[128], s_shift[128];
    if (threadIdx.x < 128) {
        int ff = threadIdx.x;
        float ssum = 0.f, qsum = 0.f;
        #pragma unroll
        for (int b = 0; b < 8; b++) {
            ssum += sums[b * 256 + ff];
            qsum += sums[b * 256 + 128 + ff];
        }
        float inv_n = 1.0f / (float)n;
        float mean = ssum * inv_n;
        float var = qsum * inv_n - mean * mean;
        float sc = gamma[ff] * (1.0f / sqrtf(var + BN_EPS));
        s_scale[ff] = sc;
        s_shift[ff] = beta[ff] - mean * sc;
    }
    __syncthreads();
    int idx = blockIdx.x * blockDim.x + threadIdx.x;
    int total = n * (DD / 4);
    if (idx >= total) return;
    int f = (idx & 31) * 4;
    float4 v = ((const float4*)X)[idx];
    float4 rv = ((const float4*)res)[idx];
    float vi[4] = {v.x, v.y, v.z, v.w};
    float ri[4] = {rv.x, rv.y, rv.z, rv.w};
    float o[4];
    #pragma unroll
    for (int j = 0; j < 4; j++) {
        float x = vi[j] * s_scale[f + j] + s_shift[f + j];
        x = fmaxf(x, 0.f);
        o[j] = x + ri[j];
    }
    ((float4*)out)[idx] = make_float4(o[0], o[1], o[2], o[3]);
}

// ---------------- attention: grid-stride waves, one atomic per block ----------------
#define ATT_BLOCKS 256
__global__ __launch_bounds__(256) void k_att(const float* __restrict__ H,
                                             const float* __restrict__ Wa,
                                             const float* __restrict__ ba,
                                             float* __restrict__ evec,
                                             float* __restrict__ Z, int n) {
    int wave = threadIdx.x >> 6;
    int lane = threadIdx.x & 63;
    int gw = blockIdx.x * 4 + wave;
    int nw = gridDim.x * 4;
    float2 wv = *(const float2*)(Wa + lane * 2);
    float bb = ba[0];
    float lsum = 0.f;
    for (int node = gw; node < n; node += nw) {
        float2 hv = *(const float2*)(H + (size_t)node * DD + lane * 2);
        float t = hv.x * wv.x + hv.y * wv.y;
        #pragma unroll
        for (int off = 1; off < 64; off <<= 1) t += __shfl_xor(t, off);
        float ev = expf(tanhf(t + bb));
        if (lane == 0) {
            evec[node] = ev;
            lsum += ev;
        }
    }
    __shared__ float part[4];
    if (lane == 0) part[wave] = lsum;
    __syncthreads();
    if (threadIdx.x == 0)
        atomicAdd(Z, part[0] + part[1] + part[2] + part[3]);
}

// ---------------- final: out = h * e / Z ----------------
__global__ __launch_bounds__(256) void k_out(const float* __restrict__ H,
                                             const float* __restrict__ evec,
                                             const float* __restrict__ Z,
                                             float* __restrict__ out, int n) {
    int idx = blockIdx.x * blockDim.x + threadIdx.x;
    int total = n * (DD / 4);
    if (idx >= total) return;
    int node = idx >> 5;
    float s = evec[node] / Z[0];
    float4 h = ((const float4*)H)[idx];
    ((float4*)out)[idx] = make_float4(h.x * s, h.y * s, h.z * s, h.w * s);
}

extern "C" void kernel_launch(void* const* d_in, const int* in_sizes, int n_in,
                              void* d_out, int out_size, void* d_ws, size_t ws_size,
                              hipStream_t stream) {
    const float* x   = (const float*)d_in[0];
    const int* eidx  = (const int*)d_in[1];
    const float* W1  = (const float*)d_in[2];
    const float* b1  = (const float*)d_in[3];
    const float* g1  = (const float*)d_in[4];
    const float* be1 = (const float*)d_in[5];
    const float* W2  = (const float*)d_in[6];
    const float* b2  = (const float*)d_in[7];
    const float* g2  = (const float*)d_in[8];
    const float* be2 = (const float*)d_in[9];
    const float* Wa  = (const float*)d_in[10];
    const float* ba  = (const float*)d_in[11];
    float* out = (float*)d_out;

    const int* srcp = eidx;
    const int* dstp = eidx + NE;

    float* bufA = (float*)d_ws;              // N*D
    float* bufB = bufA + (size_t)NN * DD;    // N*D
    float* bufC = bufB + (size_t)NN * DD;    // N*D
    float* val  = bufC + (size_t)NN * DD;    // NE
    float* dinv = val + NE;                  // NN
    float* evec = dinv + NN;                 // NN
    float* sums = evec + NN;                 // 2 layers x 8 banks x 256 = 4096
    float* Z    = sums + 4096;               // 1 (pad 64)
    int* cnt    = (int*)(Z + 64);            // NN
    int* rowp   = cnt + NN;                  // NN+1 (pad 64)
    int* cursor = rowp + NN + 64;            // NN
    int* col    = cursor + NN;               // NE
    int* bsum   = col + NE;                  // 256

    float* sumsL1 = sums;
    float* sumsL2 = sums + 2048;

    const int nscan = (NN + 255) / 256;      // 196 blocks

    // ---- CSR build (k_rowp block 0 zeroes sums+Z) ----
    hipMemsetAsync(cnt, 0, (size_t)NN * sizeof(int), stream);
    k_hist<<<(NE + 255) / 256, 256, 0, stream>>>(dstp, cnt, NE);
    k_bsum<<<nscan, 256, 0, stream>>>(cnt, bsum, NN);
    k_bscan<<<1, 256, 0, stream>>>(bsum, nscan);
    k_rowp<<<nscan, 256, 0, stream>>>(cnt, bsum, rowp, cursor, dinv, sums, NN);
    k_scatter<<<(NE + 255) / 256, 256, 0, stream>>>(srcp, dstp, cursor, col, val, dinv, NE);

    int agg_grid  = (NN + AGG_NPB - 1) / AGG_NPB;   // 3125
    int ew_grid   = (NN * (DD / 4) + 255) / 256;

    // ---- layer 1 ----
    k_gemm<<<GEMM_BLOCKS, 256, 0, stream>>>(x, W1, bufA, NN);
    k_agg<<<agg_grid, 256, 0, stream>>>(bufA, rowp, col, val, dinv, b1, bufB, sumsL1, NN);
    k_bn<<<ew_grid, 256, 0, stream>>>(bufB, x, sumsL1, g1, be1, bufC, NN);

    // ---- layer 2 ----
    k_gemm<<<GEMM_BLOCKS, 256, 0, stream>>>(bufC, W2, bufA, NN);
    k_agg<<<agg_grid, 256, 0, stream>>>(bufA, rowp, col, val, dinv, b2, bufB, sumsL2, NN);
    k_bn<<<ew_grid, 256, 0, stream>>>(bufB, bufC, sumsL2, g2, be2, bufA, NN);

    // ---- attention + output ----
    k_att<<<ATT_BLOCKS, 256, 0, stream>>>(bufA, Wa, ba, evec, Z, NN);
    k_out<<<ew_grid, 256, 0, stream>>>(bufA, evec, Z, out, NN);
}